// Round 3
// baseline (2480.334 us; speedup 1.0000x reference)
//
#include <hip/hip_runtime.h>
#include <math.h>

#define KNN 30
#define KNNS 31        // padded LDS stride for top-30 list (gcd(31,32)=1)
#define SIGMA_N 0.8f
#define THRESHV 1e-3f

// ---- grid params ----
#define G 64
#define NC (G*G*G)
#define GLO (-5.2f)
#define GH  (10.4f / 64.0f)
#define INVGH (64.0f / 10.4f)

// ws layout (bytes)
#define OFF_A     0u               // float4[M] sorted positions (w = |s|^2/2)
#define OFF_B     1048576u         // float4[M] sorted unit normals
#define OFF_CS    2097152u         // u32[NC+1] cellStart
#define OFF_CUR   3145732u         // u32[NC] cursor
#define OFF_PC    4194308u         // u32[M] pointCell
#define OFF_BS    4456452u         // u32[256] blockSums
#define WS_NEED   4457476u

// ======================= grid build =======================

__global__ void zero_u32(unsigned* __restrict__ p, int n) {
    int i = blockIdx.x * 256 + threadIdx.x;
    if (i < n) p[i] = 0u;
}

__device__ __forceinline__ int cell_of(float x, float y, float z) {
    int cx = (int)floorf((x - GLO) * INVGH);
    int cy = (int)floorf((y - GLO) * INVGH);
    int cz = (int)floorf((z - GLO) * INVGH);
    cx = min(max(cx, 0), G - 1);
    cy = min(max(cy, 0), G - 1);
    cz = min(max(cz, 0), G - 1);
    return (cz * G + cy) * G + cx;
}

__global__ void grid_count(const float* __restrict__ src, unsigned* __restrict__ counts,
                           unsigned* __restrict__ pointCell, int M) {
    int j = blockIdx.x * 256 + threadIdx.x;
    if (j >= M) return;
    int cell = cell_of(src[3*j+0], src[3*j+1], src[3*j+2]);
    pointCell[j] = (unsigned)cell;
    atomicAdd(&counts[cell], 1u);
}

__global__ void scan1(unsigned* __restrict__ cs, unsigned* __restrict__ blockSums) {
    __shared__ unsigned ts[256];
    int b = blockIdx.x, t = threadIdx.x;
    int base = b * 1024 + t * 4;
    unsigned c0 = cs[base], c1 = cs[base+1], c2 = cs[base+2], c3 = cs[base+3];
    unsigned s = c0 + c1 + c2 + c3;
    ts[t] = s;
    __syncthreads();
    for (int off = 1; off < 256; off <<= 1) {
        unsigned y = (t >= off) ? ts[t - off] : 0u;
        __syncthreads();
        ts[t] += y;
        __syncthreads();
    }
    unsigned ex = ts[t] - s;                 // block-local exclusive prefix
    cs[base]   = ex;
    cs[base+1] = ex + c0;
    cs[base+2] = ex + c0 + c1;
    cs[base+3] = ex + c0 + c1 + c2;
    if (t == 255) blockSums[b] = ts[255];
}

__global__ void scan2(unsigned* __restrict__ blockSums) {
    __shared__ unsigned ts[256];
    int t = threadIdx.x;
    unsigned v = blockSums[t];
    ts[t] = v;
    __syncthreads();
    for (int off = 1; off < 256; off <<= 1) {
        unsigned y = (t >= off) ? ts[t - off] : 0u;
        __syncthreads();
        ts[t] += y;
        __syncthreads();
    }
    blockSums[t] = ts[t] - v;                // exclusive
}

__global__ void scan3(unsigned* __restrict__ cs, unsigned* __restrict__ cur,
                      const unsigned* __restrict__ blockSums, int M) {
    int b = blockIdx.x, t = threadIdx.x;
    unsigned add = blockSums[b];
    int base = b * 1024 + t * 4;
    #pragma unroll
    for (int u = 0; u < 4; ++u) {
        unsigned v = cs[base + u] + add;
        cs[base + u] = v;
        cur[base + u] = v;
    }
    if (b == 255 && t == 255) cs[NC] = (unsigned)M;
}

__global__ void grid_scatter(const float* __restrict__ src, const float* __restrict__ snorms,
                             const unsigned* __restrict__ pointCell, unsigned* __restrict__ cur,
                             float4* __restrict__ A, float4* __restrict__ B, int M) {
    int j = blockIdx.x * 256 + threadIdx.x;
    if (j >= M) return;
    unsigned cell = pointCell[j];
    unsigned pos = atomicAdd(&cur[cell], 1u);
    float x = src[3*j+0], y = src[3*j+1], z = src[3*j+2];
    A[pos] = make_float4(x, y, z, 0.5f*(x*x + y*y + z*z));
    float nx = snorms[3*j+0], ny = snorms[3*j+1], nz = snorms[3*j+2];
    float nrm = sqrtf(nx*nx + ny*ny + nz*nz);
    float inv = 1.0f / fmaxf(nrm, 1e-8f);
    B[pos] = make_float4(nx*inv, ny*inv, nz*inv, 0.0f);
}

// ======================= search + epilogue =======================

__device__ __forceinline__ void scan_cell(const float4* __restrict__ A,
                                          unsigned st, unsigned en,
                                          float qx, float qy, float qz, float q2h,
                                          unsigned* myk, unsigned& curMax, int& maxSlot) {
    for (unsigned p = st; p < en; ++p) {
        float4 sp = A[p];
        float v = fmaf(-qx, sp.x, fmaf(-qy, sp.y, fmaf(-qz, sp.z, sp.w + q2h)));
        v = fmaxf(v, 0.0f);                               // half-d2
        unsigned key = (__float_as_uint(v) & 0xFFFF0000u) | p;
        if (key < curMax) {
            myk[maxSlot] = key;
            unsigned m = 0u; int ms = 0;
            #pragma unroll
            for (int k = 0; k < KNN; ++k) {
                unsigned x = myk[k];
                if (x > m) { m = x; ms = k; }
            }
            curMax = m; maxSlot = ms;
        }
    }
}

__global__ __launch_bounds__(64)
void knn_rimls(const float* __restrict__ qpts,
               const float4* __restrict__ A,
               const float4* __restrict__ B,
               const unsigned* __restrict__ cellStart,
               float* __restrict__ out, int N) {
    __shared__ unsigned keys[64 * KNNS];
    const int t = threadIdx.x;
    const int gq0 = blockIdx.x * 64 + t;
    const int gq = (gq0 < N) ? gq0 : (N - 1);
    const float qx = qpts[3*gq+0], qy = qpts[3*gq+1], qz = qpts[3*gq+2];
    const float q2h = 0.5f*(qx*qx + qy*qy + qz*qz);
    int cx = (int)floorf((qx - GLO) * INVGH);
    int cy = (int)floorf((qy - GLO) * INVGH);
    int cz = (int)floorf((qz - GLO) * INVGH);
    cx = min(max(cx, 0), G - 1);
    cy = min(max(cy, 0), G - 1);
    cz = min(max(cz, 0), G - 1);

    unsigned* myk = keys + t * KNNS;
    #pragma unroll
    for (int k = 0; k < KNN; ++k) myk[k] = 0xFFFFFFFFu;
    unsigned curMax = 0xFFFFFFFFu; int maxSlot = 0;

    // ---- certified ring expansion ----
    for (int s = 0; s < G; ++s) {
        if (s == 0) {
            int cell = (cz * G + cy) * G + cx;
            scan_cell(A, cellStart[cell], cellStart[cell+1], qx, qy, qz, q2h, myk, curMax, maxSlot);
        } else {
            for (int dz = -s; dz <= s; ++dz) {
                int z = cz + dz; if ((unsigned)z >= (unsigned)G) continue;
                for (int dy = -s; dy <= s; ++dy) {
                    int y = cy + dy; if ((unsigned)y >= (unsigned)G) continue;
                    bool face = (dz == -s) || (dz == s) || (dy == -s) || (dy == s);
                    int step = face ? 1 : (2 * s);
                    for (int dx = -s; dx <= s; dx += step) {
                        int x = cx + dx; if ((unsigned)x >= (unsigned)G) continue;
                        int cell = (z * G + y) * G + x;
                        unsigned st = cellStart[cell], en = cellStart[cell+1];
                        if (st != en)
                            scan_cell(A, st, en, qx, qy, qz, q2h, myk, curMax, maxSlot);
                    }
                }
            }
        }
        // min distance to any cell at Chebyshev ring > s (6 axis planes)
        float b = 1e30f;
        if (cx + s + 1 <= G - 1) b = fminf(b, GLO + (float)(cx + s + 1) * GH - qx);
        if (cx - s - 1 >= 0)     b = fminf(b, qx - (GLO + (float)(cx - s) * GH));
        if (cy + s + 1 <= G - 1) b = fminf(b, GLO + (float)(cy + s + 1) * GH - qy);
        if (cy - s - 1 >= 0)     b = fminf(b, qy - (GLO + (float)(cy - s) * GH));
        if (cz + s + 1 <= G - 1) b = fminf(b, GLO + (float)(cz + s + 1) * GH - qz);
        if (cz - s - 1 >= 0)     b = fminf(b, qz - (GLO + (float)(cz - s) * GH));
        if (b >= 1e29f) break;                   // entire grid scanned
        if (curMax != 0xFFFFFFFFu) {
            float dk = __uint_as_float(curMax & 0xFFFF0000u);   // kth half-d2 (trunc)
            b = fmaxf(b, 0.0f);
            if (dk <= 0.5f * b * b) break;
        }
    }

    // ---- bandwidth h = mean neighbor distance + eps ----
    float dsum = 0.0f;
    #pragma unroll 2
    for (int k = 0; k < KNN; ++k) {
        unsigned key = myk[k];
        unsigned p = key & 0xFFFFu;
        float4 sp = A[p];
        float px = qx - sp.x, py = qy - sp.y, pz = qz - sp.z;
        dsum += sqrtf(px*px + py*py + pz*pz);
    }
    float h = dsum * (1.0f / (float)KNN) + 1e-8f;
    float h2 = h * h;
    float c8 = -8.0f / h2;
    const float inv_sn2 = 1.0f / (SIGMA_N * SIGMA_N);

    // ---- robust refit ----
    float f = 0.0f, gx = 0.0f, gy = 0.0f, gz = 0.0f;
    bool done = false;
    for (int it = 0; it < 3; ++it) {
        if (done) break;
        float sw=0, swf=0, sgx=0, sgy=0, sgz=0, sfx=0, sfy=0, sfz=0, snx=0, sny=0, snz=0;
        for (int k = 0; k < KNN; ++k) {
            unsigned p = myk[k] & 0xFFFFu;
            float4 sp = A[p];
            float4 nn = B[p];
            float px = qx - sp.x, py = qy - sp.y, pz = qz - sp.z;
            float r2 = px*px + py*py + pz*pz;
            float fx = px*nn.x + py*nn.y + pz*nn.z;
            float tt = fmaxf(1.0f - r2 / h2, 0.0f);
            float t2 = tt * tt;
            float phi = t2 * t2;
            float gco = c8 * t2 * tt;
            float alpha = 1.0f;
            if (it > 0) {
                float dx = nn.x - gx, dy = nn.y - gy, dz = nn.z - gz;
                alpha = expf(-(dx*dx + dy*dy + dz*dz) * inv_sn2);
            }
            float w = alpha * phi;
            float g = alpha * gco;
            float gf = g * fx;
            sw  += w;       swf += w * fx;
            sgx += g*px;    sgy += g*py;    sgz += g*pz;
            sfx += gf*px;   sfy += gf*py;   sfz += gf*pz;
            snx += w*nn.x;  sny += w*nn.y;  snz += w*nn.z;
        }
        sw += 1e-8f;
        float fn  = swf / sw;
        float gnx = (sfx + snx - fn*sgx) / sw;
        float gny = (sfy + sny - fn*sgy) / sw;
        float gnz = (sfz + snz - fn*sgz) / sw;
        done = (fabsf(fn - f) < THRESHV);
        f = fn; gx = gnx; gy = gny; gz = gnz;
    }
    if (gq0 < N) {
        out[gq0] = f;
        out[N + 3*gq0 + 0] = gx;
        out[N + 3*gq0 + 1] = gy;
        out[N + 3*gq0 + 2] = gz;
    }
}

// ======================= fallback: R2 brute force =======================

#define QT 32
#define NTH 256
#define CAP 160
#define CAPS 161
#define RSEL 20

__global__ void prep_pack(const float* __restrict__ src, float4* __restrict__ dst, int M) {
    int j = blockIdx.x * 256 + threadIdx.x;
    if (j < M) {
        float x = src[3*j+0], y = src[3*j+1], z = src[3*j+2];
        dst[j] = make_float4(x, y, z, 0.5f*(x*x + y*y + z*z));
    }
}

template<bool PACKED>
__device__ __forceinline__ float4 fetch_pt(const float4* __restrict__ sp,
                                           const float* __restrict__ sv, int j) {
    if (PACKED) return sp[j];
    float x = sv[3*j+0], y = sv[3*j+1], z = sv[3*j+2];
    return make_float4(x, y, z, 0.5f*(x*x + y*y + z*z));
}

__device__ __forceinline__ void ins4(unsigned int k, unsigned int &m0, unsigned int &m1,
                                     unsigned int &m2, unsigned int &m3) {
    if (k < m3) {
        if (k < m2) {
            m3 = m2;
            if (k < m1) { m2 = m1; if (k < m0) { m1 = m0; m0 = k; } else m1 = k; }
            else m2 = k;
        } else m3 = k;
    }
}

template<bool PACKED>
__global__ __launch_bounds__(NTH)
void rimls_fused(const float* __restrict__ qpts,
                 const float* __restrict__ sverts,
                 const float* __restrict__ snorms,
                 const float4* __restrict__ spack,
                 float* __restrict__ out,
                 int N, int M)
{
    __shared__ unsigned int cand[QT * CAPS];
    __shared__ unsigned int selk[QT * KNN];
    __shared__ float4 qbuf[QT];
    __shared__ unsigned int cnt[QT];
    __shared__ unsigned int T16[QT];
    __shared__ int retryq[QT];

    const int t  = threadIdx.x;
    const int qg = t >> 4;
    const int c  = t & 15;
    const int qa = qg, qb = qg + 16;

    if (t < QT) {
        int gq = blockIdx.x * QT + t; if (gq >= N) gq = N - 1;
        float x = qpts[3*gq+0], y = qpts[3*gq+1], z = qpts[3*gq+2];
        qbuf[t] = make_float4(x, y, z, 0.5f*(x*x + y*y + z*z));
    }
    for (int i = t; i < QT * KNN; i += NTH) selk[i] = 0u;
    __syncthreads();

    const float ax = qbuf[qa].x, ay = qbuf[qa].y, az = qbuf[qa].z, aw = qbuf[qa].w;
    const float bx = qbuf[qb].x, by = qbuf[qb].y, bz = qbuf[qb].z, bw = qbuf[qb].w;

    unsigned int a0=~0u,a1=~0u,a2=~0u,a3=~0u, b0=~0u,b1=~0u,b2=~0u,b3=~0u;
    {
        const int n1 = M >> 6;
        #pragma unroll 2
        for (int i = 0; i < n1; ++i) {
            int j = (c + (i << 4)) << 2;
            float4 s = fetch_pt<PACKED>(spack, sverts, j);
            float va = fmaxf(fmaf(-ax, s.x, fmaf(-ay, s.y, fmaf(-az, s.z, s.w + aw))), 0.0f);
            float vb = fmaxf(fmaf(-bx, s.x, fmaf(-by, s.y, fmaf(-bz, s.z, s.w + bw))), 0.0f);
            unsigned int ka = (__float_as_uint(va) & 0xFFFF0000u) | (unsigned int)j;
            unsigned int kb = (__float_as_uint(vb) & 0xFFFF0000u) | (unsigned int)j;
            ins4(ka, a0, a1, a2, a3);
            ins4(kb, b0, b1, b2, b3);
        }
    }
    {
        unsigned int* mb = cand;
        mb[qa*64 + c*4 + 0] = a0; mb[qa*64 + c*4 + 1] = a1;
        mb[qa*64 + c*4 + 2] = a2; mb[qa*64 + c*4 + 3] = a3;
        mb[qb*64 + c*4 + 0] = b0; mb[qb*64 + c*4 + 1] = b1;
        mb[qb*64 + c*4 + 2] = b2; mb[qb*64 + c*4 + 3] = b3;
    }
    __syncthreads();
    if (t < QT) {
        const unsigned int* m_ = cand + t * 64;
        unsigned int kth = 0xFFFFFFFFu;
        for (int a = 0; a < 64; ++a) {
            unsigned int ka = m_[a]; int r = 0;
            for (int b = 0; b < 64; ++b) r += (m_[b] < ka) ? 1 : 0;
            if (r == RSEL - 1) kth = ka;
        }
        unsigned int tb = (kth >> 16) + 1u;
        if (tb > 0x7F00u) tb = 0x7F00u;
        T16[t] = tb; cnt[t] = 0u; retryq[t] = 1;
    }
    __syncthreads();

    const int n3 = M >> 4;
    for (int round = 0; round < 8; ++round) {
        bool aa = retryq[qa] != 0, ab = retryq[qb] != 0;
        if (aa || ab) {
            float Ta = aa ? __uint_as_float(T16[qa] << 16) : 0.0f;
            float Tb = ab ? __uint_as_float(T16[qb] << 16) : 0.0f;
            #pragma unroll 4
            for (int i = 0; i < n3; ++i) {
                int j = c + (i << 4);
                float4 s = fetch_pt<PACKED>(spack, sverts, j);
                float va = fmaxf(fmaf(-ax, s.x, fmaf(-ay, s.y, fmaf(-az, s.z, s.w + aw))), 0.0f);
                float vb = fmaxf(fmaf(-bx, s.x, fmaf(-by, s.y, fmaf(-bz, s.z, s.w + bw))), 0.0f);
                if (va < Ta) {
                    unsigned int pos = atomicAdd(&cnt[qa], 1u);
                    if (pos < (unsigned)CAP)
                        cand[qa*CAPS + pos] = (__float_as_uint(va) & 0xFFFF0000u) | (unsigned int)j;
                }
                if (vb < Tb) {
                    unsigned int pos = atomicAdd(&cnt[qb], 1u);
                    if (pos < (unsigned)CAP)
                        cand[qb*CAPS + pos] = (__float_as_uint(vb) & 0xFFFF0000u) | (unsigned int)j;
                }
            }
        }
        __syncthreads();
        int bad = 0;
        if (t < QT && retryq[t]) {
            unsigned int cc = cnt[t], tb = T16[t];
            if (cc < (unsigned)KNN) {
                if (tb < 0x7F00u) {
                    tb += (1u << 7);
                    if (tb > 0x7F00u) tb = 0x7F00u;
                    bad = 1;
                }
            } else if (cc > (unsigned)CAP && round < 4 && tb > (1u << 6)) {
                tb -= (1u << 6); bad = 1;
            }
            if (bad) { T16[t] = tb; cnt[t] = 0u; }
            else retryq[t] = 0;
        }
        if (!__syncthreads_or(bad)) break;
    }

    const int qs = t >> 3, s8 = t & 7;
    {
        unsigned int cc = cnt[qs];
        int C = (int)(cc < (unsigned)CAP ? cc : (unsigned)CAP);
        const unsigned int* cd = cand + qs * CAPS;
        for (int a = s8; a < C; a += 8) {
            unsigned int ka = cd[a]; int r = 0;
            for (int b = 0; b < C; ++b) r += (cd[b] < ka) ? 1 : 0;
            if (r < KNN) selk[qs*KNN + r] = ka;
        }
    }
    __syncthreads();

    {
        const float qx = qbuf[qs].x, qy = qbuf[qs].y, qz = qbuf[qs].z;
        float px_[4], py_[4], pz_[4], nx_[4], ny_[4], nz_[4];
        float fx_[4], phi_[4], gco_[4], r2_[4];
        float dsum = 0.0f;
        #pragma unroll
        for (int u = 0; u < 4; ++u) {
            int k = s8 + 8*u;
            bool v = (k < KNN);
            int j = v ? (int)(selk[qs*KNN + k] & 0xFFFFu) : 0;
            float4 s = fetch_pt<PACKED>(spack, sverts, j);
            float px = qx - s.x, py = qy - s.y, pz = qz - s.z;
            float r2 = px*px + py*py + pz*pz;
            float nx = snorms[3*j+0], ny = snorms[3*j+1], nz = snorms[3*j+2];
            float nrm = sqrtf(nx*nx + ny*ny + nz*nz);
            float inv = 1.0f / fmaxf(nrm, 1e-8f);
            float m = v ? 1.0f : 0.0f;
            nx *= inv * m; ny *= inv * m; nz *= inv * m;
            px_[u] = px * m; py_[u] = py * m; pz_[u] = pz * m;
            nx_[u] = nx; ny_[u] = ny; nz_[u] = nz;
            r2_[u] = r2 * m;
            fx_[u] = px_[u]*nx + py_[u]*ny + pz_[u]*nz;
            dsum += v ? sqrtf(r2) : 0.0f;
            phi_[u] = m;
        }
        dsum += __shfl_xor(dsum, 1);
        dsum += __shfl_xor(dsum, 2);
        dsum += __shfl_xor(dsum, 4);
        float h = dsum * (1.0f / (float)KNN) + 1e-8f;
        float h2 = h * h;
        float c8 = -8.0f / h2;
        #pragma unroll
        for (int u = 0; u < 4; ++u) {
            float tt = fmaxf(1.0f - r2_[u] / h2, 0.0f);
            float t2 = tt * tt;
            float valid = phi_[u];
            phi_[u] = t2 * t2 * valid;
            gco_[u] = c8 * t2 * tt * valid;
        }

        const float inv_sn2 = 1.0f / (SIGMA_N * SIGMA_N);
        float f = 0.0f, gx = 0.0f, gy = 0.0f, gz = 0.0f;
        bool done = false;
        for (int it = 0; it < 3; ++it) {
            if (done) break;
            float sw=0, swf=0, sgx=0, sgy=0, sgz=0, sfx=0, sfy=0, sfz=0, snx=0, sny=0, snz=0;
            #pragma unroll
            for (int u = 0; u < 4; ++u) {
                float alpha = 1.0f;
                if (it > 0) {
                    float dx = nx_[u]-gx, dy = ny_[u]-gy, dz = nz_[u]-gz;
                    alpha = expf(-(dx*dx + dy*dy + dz*dz) * inv_sn2);
                }
                float w = alpha * phi_[u];
                float g = alpha * gco_[u];
                float gf = g * fx_[u];
                sw  += w;          swf += w * fx_[u];
                sgx += g*px_[u];   sgy += g*py_[u];   sgz += g*pz_[u];
                sfx += gf*px_[u];  sfy += gf*py_[u];  sfz += gf*pz_[u];
                snx += w*nx_[u];   sny += w*ny_[u];   snz += w*nz_[u];
            }
            #pragma unroll
            for (int m = 1; m < 8; m <<= 1) {
                sw  += __shfl_xor(sw, m);  swf += __shfl_xor(swf, m);
                sgx += __shfl_xor(sgx, m); sgy += __shfl_xor(sgy, m); sgz += __shfl_xor(sgz, m);
                sfx += __shfl_xor(sfx, m); sfy += __shfl_xor(sfy, m); sfz += __shfl_xor(sfz, m);
                snx += __shfl_xor(snx, m); sny += __shfl_xor(sny, m); snz += __shfl_xor(snz, m);
            }
            sw += 1e-8f;
            float fn  = swf / sw;
            float gnx = (sfx + snx - fn*sgx) / sw;
            float gny = (sfy + sny - fn*sgy) / sw;
            float gnz = (sfz + snz - fn*sgz) / sw;
            float delta = fabsf(fn - f);
            f = fn; gx = gnx; gy = gny; gz = gnz;
            done = (delta < THRESHV);
        }
        if (s8 == 0) {
            int gq = blockIdx.x * QT + qs;
            if (gq < N) {
                out[gq] = f;
                out[N + 3*gq + 0] = gx;
                out[N + 3*gq + 1] = gy;
                out[N + 3*gq + 2] = gz;
            }
        }
    }
}

// ======================= launcher =======================

extern "C" void kernel_launch(void* const* d_in, const int* in_sizes, int n_in,
                              void* d_out, int out_size, void* d_ws, size_t ws_size,
                              hipStream_t stream) {
    (void)n_in; (void)out_size;
    const float* qpts   = (const float*)d_in[0];
    const float* sverts = (const float*)d_in[1];
    const float* snorms = (const float*)d_in[2];
    float* out = (float*)d_out;
    int N = in_sizes[0] / 3;
    int M = in_sizes[1] / 3;

    if (ws_size >= (size_t)WS_NEED && M <= 65536) {
        char* ws = (char*)d_ws;
        float4*   A   = (float4*)(ws + OFF_A);
        float4*   B   = (float4*)(ws + OFF_B);
        unsigned* cs  = (unsigned*)(ws + OFF_CS);
        unsigned* cur = (unsigned*)(ws + OFF_CUR);
        unsigned* pc  = (unsigned*)(ws + OFF_PC);
        unsigned* bs  = (unsigned*)(ws + OFF_BS);

        zero_u32<<<(NC + 1 + 255) / 256, 256, 0, stream>>>(cs, NC + 1);
        grid_count<<<(M + 255) / 256, 256, 0, stream>>>(sverts, cs, pc, M);
        scan1<<<256, 256, 0, stream>>>(cs, bs);
        scan2<<<1, 256, 0, stream>>>(bs);
        scan3<<<256, 256, 0, stream>>>(cs, cur, bs, M);
        grid_scatter<<<(M + 255) / 256, 256, 0, stream>>>(sverts, snorms, pc, cur, A, B, M);
        knn_rimls<<<(N + 63) / 64, 64, 0, stream>>>(qpts, A, B, cs, out, N);
    } else if (ws_size >= (size_t)M * sizeof(float4)) {
        float4* spack = (float4*)d_ws;
        prep_pack<<<(M + 255) / 256, 256, 0, stream>>>(sverts, spack, M);
        rimls_fused<true><<<(N + QT - 1) / QT, NTH, 0, stream>>>(qpts, sverts, snorms, spack, out, N, M);
    } else {
        rimls_fused<false><<<(N + QT - 1) / QT, NTH, 0, stream>>>(qpts, sverts, snorms, nullptr, out, N, M);
    }
}